// Round 8
// baseline (158.602 us; speedup 1.0000x reference)
//
#include <hip/hip_runtime.h>
#include <math.h>

#define BB 8
#define MM 2048
#define NTOT (BB*MM)
#define R2 0.04f
#define CAP 256

typedef _Float16 h8 __attribute__((ext_vector_type(8)));
typedef _Float16 h4 __attribute__((ext_vector_type(4)));
typedef float f32x4 __attribute__((ext_vector_type(4)));

// swizzled halfword index for a [64][64] f16 LDS tile (row stride 128B)
__device__ __forceinline__ int swz(int row, int col) {
  return (row << 6) + ((((col >> 3) ^ (row & 7)) << 3) | (col & 7));
}

// ---------------------------------------------------------------- helpers
__device__ __forceinline__ unsigned long long shfl_xor_u64(unsigned long long x, int off) {
  int lo = __shfl_xor((int)(unsigned)(x & 0xFFFFFFFFull), off, 64);
  int hi = __shfl_xor((int)(unsigned)(x >> 32), off, 64);
  return (((unsigned long long)(unsigned)hi) << 32) | (unsigned)lo;
}
__device__ __forceinline__ unsigned long long wave_min_u64(unsigned long long x) {
#pragma unroll
  for (int off = 32; off; off >>= 1) {
    unsigned long long o = shfl_xor_u64(x, off);
    x = (o < x) ? o : x;
  }
  return x;
}
__device__ __forceinline__ unsigned long long wave_max_u64(unsigned long long x) {
#pragma unroll
  for (int off = 32; off; off >>= 1) {
    unsigned long long o = shfl_xor_u64(x, off);
    x = (o > x) ? o : x;
  }
  return x;
}

// ---------------------------------------------------------------- kernel -1: fuse Wka=Wk@Wa, Wqa=Wq@Wa, bka, bqa, zvec
__global__ __launch_bounds__(256) void fuse_w(
    const float* __restrict__ lsw, const float* __restrict__ ldw, const float* __restrict__ attn_w,
    const float* __restrict__ lsb, const float* __restrict__ ldb,
    float* __restrict__ wka, float* __restrict__ wqa,
    float* __restrict__ bka, float* __restrict__ bqa, float* __restrict__ zvec) {
  __shared__ float sA[4096], sB[4096];
  const int tid = threadIdx.x;
  const float* src = blockIdx.x ? ldw : lsw;
  const float* sbv = blockIdx.x ? ldb : lsb;
  float* dst = blockIdx.x ? wqa : wka;
  float* dbv = blockIdx.x ? bqa : bka;
  for (int i = tid; i < 4096; i += 256) { sA[i] = src[i]; sB[i] = attn_w[i]; }
  __syncthreads();
  const int c = tid & 63, ig = tid >> 6;
#pragma unroll
  for (int r = 0; r < 16; ++r) {
    const int i = ig * 16 + r;
    float acc = 0.f;
    for (int d = 0; d < 64; ++d) acc = fmaf(sA[i * 64 + d], sB[d * 64 + c], acc);
    dst[i * 64 + c] = acc;
  }
  if (tid < 64) {
    float acc = 0.f;
    for (int d = 0; d < 64; ++d) acc = fmaf(sbv[d], sB[d * 64 + tid], acc);
    dbv[tid] = acc;
    if (blockIdx.x == 0) zvec[tid] = 0.f;
  }
}

// ---------------------------------------------------------------- kernel 0: weight images + folded BN constants
// w_img  : attn_w^T f16 swizzled [64 outcol][64 k]
// pw_img : pos_w [64 col][24 k-padded] f16
// pj_img : {lin_w, Wka, Wqa}^T hi/lo f16 swizzled, slot o at o*8192+{0,4096}
// bnc    : [pA | pB | aA | aB'] with aB' = aA*(ab + bqa - bka) + abt
__global__ __launch_bounds__(256) void prep_w(
    const float* __restrict__ attn_w, const float* __restrict__ pos_w,
    const float* __restrict__ lin_w, const float* __restrict__ wka, const float* __restrict__ wqa,
    const float* __restrict__ pos_b, const float* __restrict__ pos_g, const float* __restrict__ pos_bt,
    const float* __restrict__ attn_b, const float* __restrict__ attn_g, const float* __restrict__ attn_bt,
    const float* __restrict__ bka, const float* __restrict__ bqa,
    unsigned short* __restrict__ w_img, unsigned short* __restrict__ pw_img,
    unsigned short* __restrict__ pj_img, float* __restrict__ bnc) {
  const int idx = blockIdx.x * 256 + threadIdx.x;
  const float bninv = 1.0f / sqrtf(1.0f + 1e-5f);
  if (idx < 4096) {
    const int d = idx >> 6, cc = idx & 63;
    const int sp = swz(cc, d);
    w_img[sp] = __builtin_bit_cast(unsigned short, (_Float16)attn_w[idx]);
    const float v0 = lin_w[idx];
    const _Float16 h0 = (_Float16)v0;
    pj_img[sp] = __builtin_bit_cast(unsigned short, h0);
    pj_img[4096 + sp] = __builtin_bit_cast(unsigned short, (_Float16)(v0 - (float)h0));
    const float v1 = wka[idx];
    const _Float16 h1 = (_Float16)v1;
    pj_img[8192 + sp] = __builtin_bit_cast(unsigned short, h1);
    pj_img[12288 + sp] = __builtin_bit_cast(unsigned short, (_Float16)(v1 - (float)h1));
    const float v2 = wqa[idx];
    const _Float16 h2 = (_Float16)v2;
    pj_img[16384 + sp] = __builtin_bit_cast(unsigned short, h2);
    pj_img[20480 + sp] = __builtin_bit_cast(unsigned short, (_Float16)(v2 - (float)h2));
  }
  if (idx < 64 * 24) {
    const int col = idx / 24, k = idx - col * 24;
    const float v = (k < 6) ? pos_w[k * 64 + col] : 0.f;
    pw_img[idx] = __builtin_bit_cast(unsigned short, (_Float16)v);
  }
  if (idx < 64) {
    const float pA = pos_g[idx] * bninv;
    bnc[idx] = pA;
    bnc[64 + idx] = pA * pos_b[idx] + pos_bt[idx];
    const float aA = attn_g[idx] * bninv;
    bnc[128 + idx] = aA;
    bnc[192 + idx] = aA * (attn_b[idx] + bqa[idx] - bka[idx]) + attn_bt[idx];
  }
}

// ---------------------------------------------------------------- kernel 1: projections via 3-term f16 hi/lo MFMA
// outputs: o0 = x@lin_w + b0 (values), o1 = x@Wka (+0), o2 = x@Wqa (+0)
__global__ __launch_bounds__(256, 2) void proj_mfma(
    const float* __restrict__ x, const unsigned short* __restrict__ pj_img,
    const float* __restrict__ b0, const float* __restrict__ b1, const float* __restrict__ b2,
    float* __restrict__ o0, float* __restrict__ o1, float* __restrict__ o2) {
  __shared__ __align__(16) unsigned short s_xh[4096];
  __shared__ __align__(16) unsigned short s_xl[4096];
  __shared__ __align__(16) unsigned short s_w6[6 * 4096];
  const int tid = threadIdx.x;
  const int r0 = blockIdx.x << 6;
  for (int i = tid; i < 3072; i += 256)
    ((uint4*)s_w6)[i] = ((const uint4*)pj_img)[i];
  {
    const int row = tid >> 2, seg = tid & 3;
    const float* xr = x + (((size_t)(r0 + row)) << 6) + (seg << 4);
    float xb[16];
#pragma unroll
    for (int q = 0; q < 4; ++q) *(float4*)&xb[q * 4] = ((const float4*)xr)[q];
    h8 c0h, c1h, c0l, c1l;
#pragma unroll
    for (int e = 0; e < 8; ++e) {
      const _Float16 h0 = (_Float16)xb[e];
      c0h[e] = h0; c0l[e] = (_Float16)(xb[e] - (float)h0);
      const _Float16 h1 = (_Float16)xb[e + 8];
      c1h[e] = h1; c1l[e] = (_Float16)(xb[e + 8] - (float)h1);
    }
    const int base = row << 6;
    const int oi0 = base + ((((seg << 1) | 0) ^ (row & 7)) << 3);
    const int oi1 = base + ((((seg << 1) | 1) ^ (row & 7)) << 3);
    *(h8*)&s_xh[oi0] = c0h; *(h8*)&s_xh[oi1] = c1h;
    *(h8*)&s_xl[oi0] = c0l; *(h8*)&s_xl[oi1] = c1l;
  }
  __syncthreads();
  const int wv = tid >> 6, lane = tid & 63, lrow = lane >> 4, lcol = lane & 15;
  const int col = (wv << 4) + lcol;
  f32x4 acc[3][4];
#pragma unroll
  for (int o = 0; o < 3; ++o)
#pragma unroll
    for (int mt = 0; mt < 4; ++mt) acc[o][mt] = (f32x4){0.f, 0.f, 0.f, 0.f};
#pragma unroll
  for (int ks = 0; ks < 2; ++ks) {
    const int kc = lrow + (ks << 2);
    const int boff = (col << 6) + ((kc ^ (col & 7)) << 3);
    const h8 bh0 = *(const h8*)&s_w6[boff];
    const h8 bl0 = *(const h8*)&s_w6[4096 + boff];
    const h8 bh1 = *(const h8*)&s_w6[8192 + boff];
    const h8 bl1 = *(const h8*)&s_w6[12288 + boff];
    const h8 bh2 = *(const h8*)&s_w6[16384 + boff];
    const h8 bl2 = *(const h8*)&s_w6[20480 + boff];
#pragma unroll
    for (int mt = 0; mt < 4; ++mt) {
      const int m = (mt << 4) + lcol;
      const int aoff = (m << 6) + ((kc ^ (m & 7)) << 3);
      const h8 ah = *(const h8*)&s_xh[aoff];
      const h8 al = *(const h8*)&s_xl[aoff];
      acc[0][mt] = __builtin_amdgcn_mfma_f32_16x16x32_f16(ah, bh0, acc[0][mt], 0, 0, 0);
      acc[0][mt] = __builtin_amdgcn_mfma_f32_16x16x32_f16(al, bh0, acc[0][mt], 0, 0, 0);
      acc[0][mt] = __builtin_amdgcn_mfma_f32_16x16x32_f16(ah, bl0, acc[0][mt], 0, 0, 0);
      acc[1][mt] = __builtin_amdgcn_mfma_f32_16x16x32_f16(ah, bh1, acc[1][mt], 0, 0, 0);
      acc[1][mt] = __builtin_amdgcn_mfma_f32_16x16x32_f16(al, bh1, acc[1][mt], 0, 0, 0);
      acc[1][mt] = __builtin_amdgcn_mfma_f32_16x16x32_f16(ah, bl1, acc[1][mt], 0, 0, 0);
      acc[2][mt] = __builtin_amdgcn_mfma_f32_16x16x32_f16(ah, bh2, acc[2][mt], 0, 0, 0);
      acc[2][mt] = __builtin_amdgcn_mfma_f32_16x16x32_f16(al, bh2, acc[2][mt], 0, 0, 0);
      acc[2][mt] = __builtin_amdgcn_mfma_f32_16x16x32_f16(ah, bl2, acc[2][mt], 0, 0, 0);
    }
  }
  const float bb0 = b0[col], bb1 = b1[col], bb2 = b2[col];
#pragma unroll
  for (int mt = 0; mt < 4; ++mt)
#pragma unroll
    for (int r = 0; r < 4; ++r) {
      const size_t gi = (((size_t)(r0 + (mt << 4) + (lrow << 2) + r)) << 6) + col;
      o0[gi] = acc[0][mt][r] + bb0;
      o1[gi] = acc[1][mt][r] + bb1;
      o2[gi] = acc[2][mt][r] + bb2;
    }
}

// ---------------------------------------------------------------- kernel 2: exact radius-KNN (top-64 SET, index tiebreak)
__global__ __launch_bounds__(256) void knn_kernel(const float* __restrict__ pos,
                                                  unsigned* __restrict__ nbr) {
  __shared__ float spos[MM * 3];
  __shared__ unsigned long long slist[4][CAP];
  const int bidx = blockIdx.x;
  const int b = bidx >> 9;
  const int qblk = bidx & 511;
  const int tid = threadIdx.x;
  const float* pc = pos + (size_t)b * MM * 3;
  for (int i = tid; i < MM * 3 / 4; i += 256)
    ((float4*)spos)[i] = ((const float4*)pc)[i];
  __syncthreads();
  const int wv = tid >> 6, lane = tid & 63;
  const int q = (qblk << 2) + wv;
  const float qx = spos[q * 3 + 0], qy = spos[q * 3 + 1], qz = spos[q * 3 + 2];
  unsigned bits[32];
  unsigned cnt = 0;
#pragma unroll
  for (int i = 0; i < 32; ++i) {
    const int j = lane + (i << 6);
    const float dx = qx - spos[j * 3 + 0];
    const float dy = qy - spos[j * 3 + 1];
    const float dz = qz - spos[j * 3 + 2];
    const float d2 = __fadd_rn(__fadd_rn(__fmul_rn(dx, dx), __fmul_rn(dy, dy)), __fmul_rn(dz, dz));
    const unsigned bt = __float_as_uint(d2);
    bits[i] = bt;
    const bool val = (d2 <= R2);
    const unsigned long long mb = __ballot(val);
    if (val) {
      const unsigned off = cnt + (unsigned)__popcll(mb & ((1ull << lane) - 1ull));
      if (off < CAP) slist[wv][off] = (((unsigned long long)bt) << 32) | (unsigned)j;
    }
    cnt += (unsigned)__popcll(mb);
  }
  __syncthreads();
  unsigned outv;
  if (cnt <= 64u) {
    if (lane < (int)cnt) outv = ((unsigned)slist[wv][lane]) | 0x80000000u;
    else                 outv = 0u;
  } else if (cnt <= (unsigned)CAP) {
    unsigned long long s0, s1, s2, s3, t;
    s0 = (lane       < (int)cnt) ? slist[wv][lane      ] : ~0ull;
    s1 = (lane + 64  < (int)cnt) ? slist[wv][lane + 64 ] : ~0ull;
    s2 = (lane + 128 < (int)cnt) ? slist[wv][lane + 128] : ~0ull;
    s3 = (lane + 192 < (int)cnt) ? slist[wv][lane + 192] : ~0ull;
    if (s1 < s0) { t = s0; s0 = s1; s1 = t; }
    if (s3 < s2) { t = s2; s2 = s3; s3 = t; }
    if (s2 < s0) { t = s0; s0 = s2; s2 = t; }
    if (s3 < s1) { t = s1; s1 = s3; s3 = t; }
    if (s2 < s1) { t = s1; s1 = s2; s2 = t; }
    if (cnt <= 128u) {
      const int pops = (int)cnt - 64;
      int rl = (cnt > (unsigned)lane) ? (int)((cnt - (unsigned)lane + 63u) >> 6) : 0;
      if (rl > 4) rl = 4;
      int ti = rl - 1;
      for (int p = 0; p < pops; ++p) {
        const unsigned long long mx =
            (ti == 3) ? s3 : (ti == 2) ? s2 : (ti == 1) ? s1 : (ti == 0) ? s0 : 0ull;
        const unsigned long long g = wave_max_u64(mx);
        if (ti >= 0 && mx == g) ti--;
      }
      const int c = ti + 1;
      const unsigned long long b0 = __ballot(c & 1);
      const unsigned long long b1 = __ballot(c & 2);
      const unsigned long long b2 = __ballot(c & 4);
      const unsigned long long lm = (1ull << lane) - 1ull;
      const int pre = __popcll(b0 & lm) + 2 * __popcll(b1 & lm) + 4 * __popcll(b2 & lm);
      if (c > 0) slist[wv][pre + 0] = s0;
      if (c > 1) slist[wv][pre + 1] = s1;
      if (c > 2) slist[wv][pre + 2] = s2;
      if (c > 3) slist[wv][pre + 3] = s3;
      __asm volatile("s_waitcnt lgkmcnt(0)" ::: "memory");
      outv = ((unsigned)slist[wv][lane]) | 0x80000000u;
    } else {
      unsigned long long my = 0;
      for (int it = 0; it < 64; ++it) {
        const unsigned long long gg = wave_min_u64(s0);
        if (lane == it) my = gg;
        if (s0 == gg) { s0 = s1; s1 = s2; s2 = s3; s3 = ~0ull; }
      }
      outv = ((unsigned)my) | 0x80000000u;
    }
  } else {
    unsigned long long cur = ~0ull;
#pragma unroll
    for (int i = 0; i < 32; ++i) {
      const unsigned long long k = (((unsigned long long)bits[i]) << 32) | (unsigned)(lane + (i << 6));
      cur = (k < cur) ? k : cur;
    }
    unsigned long long my = 0;
    for (int it = 0; it < 64; ++it) {
      const unsigned long long gg = wave_min_u64(cur);
      if (lane == it) my = gg;
      if (cur == gg) {
        cur = ~0ull;
#pragma unroll
        for (int i = 0; i < 32; ++i) {
          const unsigned long long k = (((unsigned long long)bits[i]) << 32) | (unsigned)(lane + (i << 6));
          if (k > gg && k < cur) cur = k;
        }
      }
    }
    const float d2s = __uint_as_float((unsigned)(my >> 32));
    outv = ((unsigned)my) | ((d2s <= R2) ? 0x80000000u : 0u);
  }
  nbr[((size_t)(b * MM + q)) * 64 + lane] = outv;
}

// ---------------------------------------------------------------- kernel 3: fused transformer conv (algebraic KW/QW form)
// alpha = delta@Wa + QWr_q - KWr_j + const (folded into bnc); KW/V gathered per-element from L2.
__global__ __launch_bounds__(256, 4) void ptc_kernel(
    const float* __restrict__ pos, const float* __restrict__ nrm,
    const float* __restrict__ vv, const float* __restrict__ kwr, const float* __restrict__ qwr,
    const unsigned* __restrict__ nbr,
    const unsigned short* __restrict__ w_img, const unsigned short* __restrict__ pw_img,
    const float* __restrict__ bnc,
    float* __restrict__ out) {
  __shared__ __align__(16) unsigned short s_w[4096];       // 8KB swizzled attn wT
  __shared__ __align__(16) unsigned short s_t[4096];       // 8KB delta tile [n][d] f16
  __shared__ __align__(16) unsigned short s_pw[64 * 24];   // 3KB
  __shared__ __align__(16) unsigned short s_relh[64 * 24]; // 3KB
  const int qi = blockIdx.x;
  const int b = qi >> 11;
  const int tid = threadIdx.x;
  const int wv = tid >> 6, lane = tid & 63;
  const int lrow = lane >> 4, lcol = lane & 15;
  const int col = (wv << 4) + lcol;

  // ---- neighbor ids straight to regs (4 x dwordx4 of this block's nbr row)
  uint4 sraw[4];
#pragma unroll
  for (int mt = 0; mt < 4; ++mt)
    sraw[mt] = *(const uint4*)&nbr[(size_t)qi * 64 + (mt << 4) + (lrow << 2)];

  // ---- issue all scattered KW/V gathers up-front (L2-hit latency hides under MFMAs)
  float kwv[16], vvv[16];
  unsigned mbits = 0;
#pragma unroll
  for (int mt = 0; mt < 4; ++mt) {
    const unsigned sv[4] = {sraw[mt].x, sraw[mt].y, sraw[mt].z, sraw[mt].w};
#pragma unroll
    for (int r = 0; r < 4; ++r) {
      const int i = (mt << 2) + r;
      const unsigned s = sv[r];
      mbits |= ((s >> 31) & 1u) << i;
      const size_t jg = ((size_t)(b << 11) + (size_t)(s & 0x7FFFFFFFu));
      kwv[i] = kwr[(jg << 6) + col];
      vvv[i] = vv[(jg << 6) + col];
    }
  }
  const float qwc = qwr[(size_t)qi * 64 + col];

  // ---- stage weight images
  ((uint4*)s_w)[tid] = ((const uint4*)w_img)[tid];
  ((uint4*)s_w)[tid + 256] = ((const uint4*)w_img)[tid + 256];
  if (tid < 192) ((uint4*)s_pw)[tid] = ((const uint4*)pw_img)[tid];

  // ---- rel rows (f16, zero-padded to k=16)
  if (tid < 64) {
    const unsigned s = nbr[(size_t)qi * 64 + tid];
    const int jg = (b << 11) + (int)(s & 0x7FFFFFFFu);
    h8 hv;
    hv[0] = (_Float16)(pos[(size_t)qi * 3 + 0] - pos[(size_t)jg * 3 + 0]);
    hv[1] = (_Float16)(pos[(size_t)qi * 3 + 1] - pos[(size_t)jg * 3 + 1]);
    hv[2] = (_Float16)(pos[(size_t)qi * 3 + 2] - pos[(size_t)jg * 3 + 2]);
    hv[3] = (_Float16)(nrm[(size_t)qi * 3 + 0] - nrm[(size_t)jg * 3 + 0]);
    hv[4] = (_Float16)(nrm[(size_t)qi * 3 + 1] - nrm[(size_t)jg * 3 + 1]);
    hv[5] = (_Float16)(nrm[(size_t)qi * 3 + 2] - nrm[(size_t)jg * 3 + 2]);
    hv[6] = (_Float16)0.f; hv[7] = (_Float16)0.f;
    *(h8*)&s_relh[tid * 24] = hv;
    h8 zz = (h8)(_Float16)0.f;
    *(h8*)&s_relh[tid * 24 + 8] = zz;
  }
  __syncthreads();

  // ---- MFMA1: delta-pre = rel @ pos_w (K padded to 16)
  f32x4 dacc[4];
  {
    const h4 bpw = *(const h4*)&s_pw[col * 24 + (lrow << 2)];
#pragma unroll
    for (int mt = 0; mt < 4; ++mt) {
      const h4 ar = *(const h4*)&s_relh[((mt << 4) + lcol) * 24 + (lrow << 2)];
      dacc[mt] = __builtin_amdgcn_mfma_f32_16x16x16f16(ar, bpw, (f32x4){0.f, 0.f, 0.f, 0.f}, 0, 0, 0);
    }
  }

  // ---- delta = relu(bn(.)) kept in regs; f16 copy into transpose tile for MFMA2
  const float pA = bnc[col], pB = bnc[64 + col];
  const float aA = bnc[128 + col];
  const float aBq = fmaf(aA, qwc, bnc[192 + col]);
  float def[16];
#pragma unroll
  for (int mt = 0; mt < 4; ++mt) {
#pragma unroll
    for (int r = 0; r < 4; ++r) {
      const int i = (mt << 2) + r;
      const int n = (mt << 4) + (lrow << 2) + r;
      const float de = fmaxf(fmaf(pA, dacc[mt][r], pB), 0.f);
      def[i] = de;
      *(_Float16*)&s_t[swz(n, col)] = (_Float16)de;
    }
  }
  __syncthreads();

  // ---- MFMA2: deltaW = delta @ attn_w
  f32x4 acc[4];
#pragma unroll
  for (int mt = 0; mt < 4; ++mt) acc[mt] = (f32x4){0.f, 0.f, 0.f, 0.f};
#pragma unroll
  for (int ks = 0; ks < 2; ++ks) {
    const int kc = lrow + (ks << 2);
    const h8 bh = *(const h8*)&s_w[(col << 6) + ((kc ^ (col & 7)) << 3)];
#pragma unroll
    for (int mt = 0; mt < 4; ++mt) {
      const int m = (mt << 4) + lcol;
      const h8 ah = *(const h8*)&s_t[(m << 6) + ((kc ^ (m & 7)) << 3)];
      acc[mt] = __builtin_amdgcn_mfma_f32_16x16x32_f16(ah, bh, acc[mt], 0, 0, 0);
    }
  }

  // ---- alpha = bn(deltaW - KW + QW + consts), relu, mask; per-channel softmax
  float a[16];
  float pm = -INFINITY;
#pragma unroll
  for (int mt = 0; mt < 4; ++mt) {
#pragma unroll
    for (int r = 0; r < 4; ++r) {
      const int i = (mt << 2) + r;
      const float al = fmaxf(fmaf(aA, acc[mt][r] - kwv[i], aBq), 0.f);
      const float av = ((mbits >> i) & 1u) ? al : -INFINITY;
      a[i] = av;
      pm = fmaxf(pm, av);
    }
  }
  pm = fmaxf(pm, __shfl_xor(pm, 16, 64));
  pm = fmaxf(pm, __shfl_xor(pm, 32, 64));
  float ps = 0.f;
#pragma unroll
  for (int i = 0; i < 16; ++i) {
    const float e = __expf(a[i] - pm);   // masked -> exp(-inf) = 0
    a[i] = e;
    ps += e;
  }
  ps += __shfl_xor(ps, 16, 64);
  ps += __shfl_xor(ps, 32, 64);

  // ---- out[col] = (sum_n e_n * (v_n[col] + delta[n][col])) / sum_n e_n  (all regs)
  float o = 0.f;
#pragma unroll
  for (int i = 0; i < 16; ++i) o = fmaf(a[i], vvv[i] + def[i], o);
  o += __shfl_xor(o, 16, 64);
  o += __shfl_xor(o, 32, 64);
  if (lrow == 0) out[(size_t)qi * 64 + col] = o * (1.0f / ps);
}

// ---------------------------------------------------------------- launch
extern "C" void kernel_launch(void* const* d_in, const int* in_sizes, int n_in,
                              void* d_out, int out_size, void* d_ws, size_t ws_size,
                              hipStream_t stream) {
  const float* x      = (const float*)d_in[0];
  const float* pos    = (const float*)d_in[1];
  const float* nrm    = (const float*)d_in[2];
  const float* lin_w  = (const float*)d_in[4];
  const float* lin_b  = (const float*)d_in[5];
  const float* lsw    = (const float*)d_in[6];
  const float* lsb    = (const float*)d_in[7];
  const float* ldw    = (const float*)d_in[8];
  const float* ldb    = (const float*)d_in[9];
  const float* pos_w  = (const float*)d_in[10];
  const float* pos_b  = (const float*)d_in[11];
  const float* pos_g  = (const float*)d_in[12];
  const float* pos_bt = (const float*)d_in[13];
  const float* attn_w = (const float*)d_in[14];
  const float* attn_b = (const float*)d_in[15];
  const float* attn_g = (const float*)d_in[16];
  const float* attn_bt= (const float*)d_in[17];
  float* out = (float*)d_out;

  float* wsf = (float*)d_ws;
  float* v    = wsf;                                  // x@lin_w + b
  float* kwr  = wsf + (size_t)NTOT * 64;              // x@(Wk@Wa)
  float* qwrp = wsf + (size_t)2 * NTOT * 64;          // x@(Wq@Wa)
  unsigned* nbr = (unsigned*)(wsf + (size_t)3 * NTOT * 64);
  unsigned short* w_img  = (unsigned short*)(wsf + (size_t)4 * NTOT * 64);
  unsigned short* pw_img = w_img + 4096;
  unsigned short* pj_img = pw_img + 1536;
  float* bnc  = (float*)(pj_img + 24576);
  float* wka  = bnc + 256;
  float* wqa  = wka + 4096;
  float* bka  = wqa + 4096;
  float* bqa  = bka + 64;
  float* zvec = bqa + 64;

  fuse_w<<<2, 256, 0, stream>>>(lsw, ldw, attn_w, lsb, ldb, wka, wqa, bka, bqa, zvec);
  prep_w<<<16, 256, 0, stream>>>(attn_w, pos_w, lin_w, wka, wqa,
                                 pos_b, pos_g, pos_bt, attn_b, attn_g, attn_bt,
                                 bka, bqa, w_img, pw_img, pj_img, bnc);
  proj_mfma<<<NTOT / 64, 256, 0, stream>>>(
      x, pj_img, lin_b, zvec, zvec, v, kwr, qwrp);
  knn_kernel<<<BB * (MM / 4), 256, 0, stream>>>(pos, nbr);
  ptc_kernel<<<NTOT, 256, 0, stream>>>(
      pos, nrm, v, kwr, qwrp, nbr, w_img, pw_img, bnc, out);
}